// Round 17
// baseline (67.462 us; speedup 1.0000x reference)
//
#include <hip/hip_runtime.h>

// LLR denoiser — R17 DIAGNOSTIC ROUND (headline time deliberately inflated):
//   llr_zs     : unchanged producer (~12.4us).
//   cpy_strip  : pure out=x copy in llr_strip's EXACT access pattern
//                (no gather/LDS/compute) — isolates the data-movement cost.
//   cpy_lin    : pure linear grid-stride copy — known-good BW anchor.
//   llr_strip  : R15 structure, pw-clamp bug FIXED (final correct output).
// rocprof per-dispatch rows give all four durations in one round.

#define NBATCH  2
#define NCH     16
#define HDIM    512
#define WDIM    512
#define NPH     127
#define NPW     127
#define NPATCH  (NBATCH * NPH * NPW)
#define NCELL   128
#define THS     0.1f
#define NSIT    8

typedef short bf16x8 __attribute__((ext_vector_type(8)));
typedef float f32x4  __attribute__((ext_vector_type(4)));

#define MFMA(a,b,c) __builtin_amdgcn_mfma_f32_16x16x32_bf16((a),(b),(c),0,0,0)

static __device__ inline short f2bf(float x) {
  return __builtin_bit_cast(short, (__bf16)x);   // native RNE convert
}
static __device__ inline float blo2f(unsigned int v) {
  return __builtin_bit_cast(float, v << 16);
}
static __device__ inline float bhi2f(unsigned int v) {
  return __builtin_bit_cast(float, v & 0xffff0000u);
}
static __device__ inline unsigned int pack2bf(float lo, float hi) {
  unsigned int a = (unsigned short)f2bf(lo);
  unsigned int b = (unsigned short)f2bf(hi);
  return (b << 16) | a;
}

// bijective XCD swizzle (m204) — used by llr_zs only
static __device__ inline int xcd_swz(int b, int nwg) {
  const int q = nwg >> 3, r = nwg & 7;
  const int x = b & 7, lo = b >> 3;
  return (x < r ? x * (q + 1) : r * (q + 1) + (x - r) * q) + lo;
}

static __device__ inline bf16x8 fragc(f32x4 v) {
  // symmetric-matrix C-layout -> MFMA A/B fragment (16 nonzero k-slots)
  bf16x8 r;
  r[0] = f2bf(v[0]); r[1] = f2bf(v[1]); r[2] = f2bf(v[2]); r[3] = f2bf(v[3]);
  r[4] = 0; r[5] = 0; r[6] = 0; r[7] = 0;
  return r;
}

// ---------------- Phase 1: per-patch scaled inverse-sqrt matrices ----------
#define ZS_NBLK ((NPATCH + 3) / 4)
__global__ __launch_bounds__(256) void llr_zs(const float* __restrict__ x,
                                              uint2* __restrict__ zs) {
  const int blk = xcd_swz(blockIdx.x, ZS_NBLK);
  const int pid = blk * 4 + (threadIdx.x >> 6);  // one wave per patch
  if (pid >= NPATCH) return;
  const int bi  = pid / (NPH * NPW);
  const int pr  = pid % (NPH * NPW);
  const int ph  = pr / NPW, pw = pr % NPW;
  const int h0  = ph * 4, w0 = pw * 4;
  const int l   = threadIdx.x & 63;
  const int j   = l & 15;
  const int u   = l >> 4;

  const size_t HW = (size_t)HDIM * WDIM;
  const float* xb = x + (size_t)bi * NCH * HW;

  const float* pb = xb + (size_t)j * HW + (size_t)h0 * WDIM + w0;
  const int dh0 = (u >> 1), dw0 = 4 * (u & 1);
  float4 q0 = *(const float4*)(pb + (size_t)(dh0 + 0) * WDIM + dw0);
  float4 q1 = *(const float4*)(pb + (size_t)(dh0 + 2) * WDIM + dw0);
  float4 q2 = *(const float4*)(pb + (size_t)(dh0 + 4) * WDIM + dw0);
  float4 q3 = *(const float4*)(pb + (size_t)(dh0 + 6) * WDIM + dw0);

  bf16x8 m0, m1;
  m0[0]=f2bf(q0.x); m0[1]=f2bf(q0.y); m0[2]=f2bf(q0.z); m0[3]=f2bf(q0.w);
  m0[4]=f2bf(q1.x); m0[5]=f2bf(q1.y); m0[6]=f2bf(q1.z); m0[7]=f2bf(q1.w);
  m1[0]=f2bf(q2.x); m1[1]=f2bf(q2.y); m1[2]=f2bf(q2.z); m1[3]=f2bf(q2.w);
  m1[4]=f2bf(q3.x); m1[5]=f2bf(q3.y); m1[6]=f2bf(q3.z); m1[7]=f2bf(q3.w);

  f32x4 g = {0.f, 0.f, 0.f, 0.f};
  g = MFMA(m0, m0, g);
  g = MFMA(m1, m1, g);

  float s2 = g[0]*g[0] + g[1]*g[1] + g[2]*g[2] + g[3]*g[3];
  #pragma unroll
  for (int m = 32; m >= 1; m >>= 1) s2 += __shfl_xor(s2, m, 64);

  uint2 wv = {0u, 0u};
  if (s2 > 1e-20f) {
    const float invf  = rsqrtf(s2);
    const float gsc   = 2.0f * invf;
    const float alpha = THS * sqrtf(gsc);

    f32x4 Yc, Zc;
    #pragma unroll
    for (int r = 0; r < 4; ++r) {
      Yc[r] = g[r] * gsc;
      Zc[r] = (4 * u + r == j) ? 1.0f : 0.0f;
    }

    const f32x4 zero = {0.f, 0.f, 0.f, 0.f};
    for (int it = 0; it < NSIT - 1; ++it) {
      bf16x8 yF = fragc(Yc), zF = fragc(Zc);
      f32x4 t  = MFMA(zF, yF, zero);
      bf16x8 tF = fragc(t);
      f32x4 py = MFMA(yF, tF, zero);
      f32x4 pz = MFMA(tF, zF, zero);
      #pragma unroll
      for (int r = 0; r < 4; ++r) {
        Yc[r] = 1.5f * Yc[r] - 0.5f * py[r];
        Zc[r] = 1.5f * Zc[r] - 0.5f * pz[r];
      }
    }
    {
      bf16x8 yF = fragc(Yc), zF = fragc(Zc);
      f32x4 t  = MFMA(zF, yF, zero);
      bf16x8 tF = fragc(t);
      f32x4 pz = MFMA(tF, zF, zero);
      #pragma unroll
      for (int r = 0; r < 4; ++r) Zc[r] = 1.5f * Zc[r] - 0.5f * pz[r];
    }

    wv.x = pack2bf(alpha * Zc[0], alpha * Zc[1]);
    wv.y = pack2bf(alpha * Zc[2], alpha * Zc[3]);
  }
  zs[(size_t)pid * 64 + l] = wv;
}

// ---------------- ABLATION A: strip-pattern pure copy ----------------------
// Identical block/thread/addressing to llr_strip's x-load and out-store.
#define ST_NBLK (NBATCH * NCELL)   // 256
__global__ __launch_bounds__(512) void cpy_strip(const float* __restrict__ x,
                                                 float* __restrict__ out) {
  const int bid = blockIdx.x;
  const int ci  = bid & 127;
  const int bi  = bid >> 7;
  const int t   = threadIdx.x;
  const int r   = t >> 7;
  const int q   = t & 127;
  const int h   = 4 * ci + r;

  const size_t HW = (size_t)HDIM * WDIM;
  const float* px = x + (size_t)bi * NCH * HW + (size_t)h * WDIM + 4 * q;
  float* po = out + (size_t)bi * NCH * HW + (size_t)h * WDIM + 4 * q;
  #pragma unroll
  for (int e = 0; e < 16; ++e) {
    float4 v = *(const float4*)(px + (size_t)e * HW);
    *(float4*)(po + (size_t)e * HW) = v;
  }
}

// ---------------- ABLATION B: linear pure copy (BW anchor) -----------------
__global__ __launch_bounds__(256) void cpy_lin(const float* __restrict__ x,
                                               float* __restrict__ out) {
  const size_t n4 = (size_t)NBATCH * NCH * HDIM * WDIM / 4;
  for (size_t i = blockIdx.x * (size_t)blockDim.x + threadIdx.x; i < n4;
       i += (size_t)gridDim.x * blockDim.x)
    ((float4*)out)[i] = ((const float4*)x)[i];
}

// ---------------- Phase 2: full-strip apply (R15 + clamp fix) --------------
__global__ __launch_bounds__(512, 2) void llr_strip(const float* __restrict__ x,
                                                    const uint2* __restrict__ zs,
                                                    float* __restrict__ out) {
  __shared__ unsigned int RS[129 * 132];       // 68.1 KB

  const int bid = blockIdx.x;
  const int ci  = bid & 127;
  const int bi  = bid >> 7;
  const int t   = threadIdx.x;
  const int w8  = t >> 6;
  const int l   = t & 63;

  const size_t HW = (size_t)HDIM * WDIM;
  const float* xb = x + (size_t)bi * NCH * HW;
  float* ob = out + (size_t)bi * NCH * HW;

  // ---- gather: 129 rowsum slots (slot s -> patch col pw = s-1)
  {
    const int u = l >> 4, j = l & 15;
    const uint2* zb = zs + (size_t)bi * NPH * NPW * 64;
    const bool vh0 = (ci > 0), vh1 = (ci < NPH);
    const int ph0c = vh0 ? ci - 1 : 0;
    const int ph1c = vh1 ? ci : NPH - 1;
    for (int s = w8; s < 129; s += 8) {
      const int pw = s - 1;
      const bool vw = ((unsigned)pw <= (unsigned)(NPW - 1));  // FIXED: pw in [0,126]
      const int pwc = vw ? pw : 0;
      uint2 z0 = zb[((size_t)ph0c * NPW + pwc) * 64 + l];
      uint2 z1 = zb[((size_t)ph1c * NPW + pwc) * 64 + l];
      if (!(vw && vh0)) { z0.x = 0u; z0.y = 0u; }
      if (!(vw && vh1)) { z1.x = 0u; z1.y = 0u; }
      const float a0 = blo2f(z0.x) + blo2f(z1.x);
      const float a1 = bhi2f(z0.x) + bhi2f(z1.x);
      const float a2 = blo2f(z0.y) + blo2f(z1.y);
      const float a3 = bhi2f(z0.y) + bhi2f(z1.y);
      RS[s * 132 + 32 * u + j]      = pack2bf(a0, a1);
      RS[s * 132 + 32 * u + 16 + j] = pack2bf(a2, a3);
    }
  }
  __syncthreads();

  // ---- compute: thread (r, q) = cell q, row h
  const int r = t >> 7;
  const int q = t & 127;
  const int h = 4 * ci + r;

  const float* px = xb + (size_t)h * WDIM + 4 * q;
  float4 xv[16];
  #pragma unroll
  for (int e = 0; e < 16; ++e) xv[e] = *(const float4*)(px + (size_t)e * HW);

  const float cnth = 2.0f - (ci == 0) - (ci == NCELL - 1);
  const float cntw = 2.0f - (q == 0) - (q == NCELL - 1);
  const float sc = 1.0f / (cnth * cntw);

  float* po = ob + (size_t)h * WDIM + 4 * q;
  #pragma unroll
  for (int p = 0; p < 8; ++p) {
    float4 d0 = {0.f, 0.f, 0.f, 0.f};
    float4 d1 = {0.f, 0.f, 0.f, 0.f};
    #pragma unroll
    for (int k = 0; k < 4; ++k) {
      const uint4 A = *(const uint4*)&RS[q * 132 + 16 * p + 4 * k];
      const uint4 B = *(const uint4*)&RS[(q + 1) * 132 + 16 * p + 4 * k];
      const unsigned int aa[4] = {A.x, A.y, A.z, A.w};
      const unsigned int bb[4] = {B.x, B.y, B.z, B.w};
      #pragma unroll
      for (int c = 0; c < 4; ++c) {
        const int e = 4 * k + c;
        const float wlo = blo2f(aa[c]) + blo2f(bb[c]);
        const float whi = bhi2f(aa[c]) + bhi2f(bb[c]);
        d0.x += wlo * xv[e].x; d0.y += wlo * xv[e].y;
        d0.z += wlo * xv[e].z; d0.w += wlo * xv[e].w;
        d1.x += whi * xv[e].x; d1.y += whi * xv[e].y;
        d1.z += whi * xv[e].z; d1.w += whi * xv[e].w;
      }
    }
    const int c0 = 2 * p, c1 = 2 * p + 1;
    float4 o0, o1;
    o0.x = xv[c0].x - sc * d0.x; o0.y = xv[c0].y - sc * d0.y;
    o0.z = xv[c0].z - sc * d0.z; o0.w = xv[c0].w - sc * d0.w;
    o1.x = xv[c1].x - sc * d1.x; o1.y = xv[c1].y - sc * d1.y;
    o1.z = xv[c1].z - sc * d1.z; o1.w = xv[c1].w - sc * d1.w;
    *(float4*)(po + (size_t)c0 * HW) = o0;
    *(float4*)(po + (size_t)c1 * HW) = o1;
  }
}

extern "C" void kernel_launch(void* const* d_in, const int* in_sizes, int n_in,
                              void* d_out, int out_size, void* d_ws, size_t ws_size,
                              hipStream_t stream) {
  const float* x = (const float*)d_in[0];
  float* out = (float*)d_out;
  uint2* zs = (uint2*)d_ws;                    // 32258*512B = 16.5 MB

  llr_zs<<<dim3(ZS_NBLK), dim3(256), 0, stream>>>(x, zs);
  // --- ablation dispatches (outputs overwritten by llr_strip below) ---
  cpy_strip<<<dim3(ST_NBLK), dim3(512), 0, stream>>>(x, out);
  cpy_lin<<<dim3(2048), dim3(256), 0, stream>>>(x, out);
  // --- real phase 2 (writes every output element -> final state correct) ---
  llr_strip<<<dim3(ST_NBLK), dim3(512), 0, stream>>>(x, zs, out);
}

// Round 18
// 48.543 us; speedup vs baseline: 1.3897x; 1.3897x over previous
//
#include <hip/hip_runtime.h>

// LLR denoiser, two-phase, atomic-free:
//   Phase 1 (llr_zs): per patch p, S_p = alpha_p * Zhat_p (16x16 ~ THS*G^{-1/2})
//            via register-resident Newton-Schulz; bf16 to ws. XCD-swizzled.
//   Phase 2 (llr_q): quarter-strip (4 rows x 128 px = 32 cells), 512 thr.
//            R17 ablation: movement in this pattern = copy speed (~10us);
//            the 25us excess was serialized gather+barrier (1 block/CU) +
//            8-way LDS conflicts (pitch 132: lanes q=q0 mod 8 same bank) +
//            bf16 unpack VALU. Fixes: (1) wave = 16 cells x 4 lanes ->
//            4-lane BROADCAST RS reads, rows spread 4c%32 banks (2-way=free);
//            (2) f32 rowsums in LDS (no unpack in matvec); (3) 34KB LDS ->
//            4 blocks/CU so blocks overlap each other's phases; (4) VGPR<=64.

#define NBATCH  2
#define NCH     16
#define HDIM    512
#define WDIM    512
#define NPH     127
#define NPW     127
#define NPATCH  (NBATCH * NPH * NPW)
#define NCELL   128
#define THS     0.1f
#define NSIT    8

typedef short bf16x8 __attribute__((ext_vector_type(8)));
typedef float f32x4  __attribute__((ext_vector_type(4)));

#define MFMA(a,b,c) __builtin_amdgcn_mfma_f32_16x16x32_bf16((a),(b),(c),0,0,0)

static __device__ inline short f2bf(float x) {
  return __builtin_bit_cast(short, (__bf16)x);   // native RNE convert
}
static __device__ inline float blo2f(unsigned int v) {
  return __builtin_bit_cast(float, v << 16);
}
static __device__ inline float bhi2f(unsigned int v) {
  return __builtin_bit_cast(float, v & 0xffff0000u);
}
static __device__ inline unsigned int pack2bf(float lo, float hi) {
  unsigned int a = (unsigned short)f2bf(lo);
  unsigned int b = (unsigned short)f2bf(hi);
  return (b << 16) | a;
}

// bijective XCD swizzle (m204) — used by llr_zs only
static __device__ inline int xcd_swz(int b, int nwg) {
  const int q = nwg >> 3, r = nwg & 7;
  const int x = b & 7, lo = b >> 3;
  return (x < r ? x * (q + 1) : r * (q + 1) + (x - r) * q) + lo;
}

static __device__ inline bf16x8 fragc(f32x4 v) {
  // symmetric-matrix C-layout -> MFMA A/B fragment (16 nonzero k-slots)
  bf16x8 r;
  r[0] = f2bf(v[0]); r[1] = f2bf(v[1]); r[2] = f2bf(v[2]); r[3] = f2bf(v[3]);
  r[4] = 0; r[5] = 0; r[6] = 0; r[7] = 0;
  return r;
}

// ---------------- Phase 1: per-patch scaled inverse-sqrt matrices ----------
#define ZS_NBLK ((NPATCH + 3) / 4)
__global__ __launch_bounds__(256) void llr_zs(const float* __restrict__ x,
                                              uint2* __restrict__ zs) {
  const int blk = xcd_swz(blockIdx.x, ZS_NBLK);
  const int pid = blk * 4 + (threadIdx.x >> 6);  // one wave per patch
  if (pid >= NPATCH) return;
  const int bi  = pid / (NPH * NPW);
  const int pr  = pid % (NPH * NPW);
  const int ph  = pr / NPW, pw = pr % NPW;
  const int h0  = ph * 4, w0 = pw * 4;
  const int l   = threadIdx.x & 63;
  const int j   = l & 15;
  const int u   = l >> 4;

  const size_t HW = (size_t)HDIM * WDIM;
  const float* xb = x + (size_t)bi * NCH * HW;

  const float* pb = xb + (size_t)j * HW + (size_t)h0 * WDIM + w0;
  const int dh0 = (u >> 1), dw0 = 4 * (u & 1);
  float4 q0 = *(const float4*)(pb + (size_t)(dh0 + 0) * WDIM + dw0);
  float4 q1 = *(const float4*)(pb + (size_t)(dh0 + 2) * WDIM + dw0);
  float4 q2 = *(const float4*)(pb + (size_t)(dh0 + 4) * WDIM + dw0);
  float4 q3 = *(const float4*)(pb + (size_t)(dh0 + 6) * WDIM + dw0);

  bf16x8 m0, m1;
  m0[0]=f2bf(q0.x); m0[1]=f2bf(q0.y); m0[2]=f2bf(q0.z); m0[3]=f2bf(q0.w);
  m0[4]=f2bf(q1.x); m0[5]=f2bf(q1.y); m0[6]=f2bf(q1.z); m0[7]=f2bf(q1.w);
  m1[0]=f2bf(q2.x); m1[1]=f2bf(q2.y); m1[2]=f2bf(q2.z); m1[3]=f2bf(q2.w);
  m1[4]=f2bf(q3.x); m1[5]=f2bf(q3.y); m1[6]=f2bf(q3.z); m1[7]=f2bf(q3.w);

  f32x4 g = {0.f, 0.f, 0.f, 0.f};
  g = MFMA(m0, m0, g);
  g = MFMA(m1, m1, g);

  float s2 = g[0]*g[0] + g[1]*g[1] + g[2]*g[2] + g[3]*g[3];
  #pragma unroll
  for (int m = 32; m >= 1; m >>= 1) s2 += __shfl_xor(s2, m, 64);

  uint2 wv = {0u, 0u};
  if (s2 > 1e-20f) {
    const float invf  = rsqrtf(s2);
    const float gsc   = 2.0f * invf;           // normalize by t = f/2
    const float alpha = THS * sqrtf(gsc);

    f32x4 Yc, Zc;
    #pragma unroll
    for (int r = 0; r < 4; ++r) {
      Yc[r] = g[r] * gsc;
      Zc[r] = (4 * u + r == j) ? 1.0f : 0.0f;
    }

    const f32x4 zero = {0.f, 0.f, 0.f, 0.f};
    for (int it = 0; it < NSIT - 1; ++it) {
      bf16x8 yF = fragc(Yc), zF = fragc(Zc);
      f32x4 t  = MFMA(zF, yF, zero);
      bf16x8 tF = fragc(t);
      f32x4 py = MFMA(yF, tF, zero);
      f32x4 pz = MFMA(tF, zF, zero);
      #pragma unroll
      for (int r = 0; r < 4; ++r) {
        Yc[r] = 1.5f * Yc[r] - 0.5f * py[r];
        Zc[r] = 1.5f * Zc[r] - 0.5f * pz[r];
      }
    }
    {
      bf16x8 yF = fragc(Yc), zF = fragc(Zc);
      f32x4 t  = MFMA(zF, yF, zero);
      bf16x8 tF = fragc(t);
      f32x4 pz = MFMA(tF, zF, zero);
      #pragma unroll
      for (int r = 0; r < 4; ++r) Zc[r] = 1.5f * Zc[r] - 0.5f * pz[r];
    }

    wv.x = pack2bf(alpha * Zc[0], alpha * Zc[1]);
    wv.y = pack2bf(alpha * Zc[2], alpha * Zc[3]);
  }
  zs[(size_t)pid * 64 + l] = wv;
}

// ---------------- Phase 2: quarter-strip apply -----------------------------
// Block = (bi, ci, qs): 4 rows x 128 px = 32 cells. 512 threads:
//   thread t: r = t>>7 (pixel row), px = t&127, cell c = px>>2.
//   Wave = 64 consecutive px = 16 cells x 4 lanes -> RS reads broadcast x4,
//   rows at banks 4c%32 -> worst 2-way (free).
// Gather: 33 f32 rowsum slots (pw = qs*32-1+s); slot s by wave s%8; each
//   slot = 2 coalesced uint2 zs loads summed -> f32, scattered b32 writes.
// LDS slot layout: RS[s*260 + 16*co + ci_] = rowsum W[co][ci_]; pitch 260
//   (65x16B) keeps float4 reads aligned, rows bank-spread.
#define Q_NBLK (NBATCH * NCELL * 4)   // 1024 -> 4 blocks/CU
__global__ __launch_bounds__(512, 8) void llr_q(const float* __restrict__ x,
                                                const uint2* __restrict__ zs,
                                                float* __restrict__ out) {
  __shared__ float RS[33 * 260];               // 34.3 KB

  const int bid = blockIdx.x;                  // bi*512 + ci*4 + qs
  const int qs  = bid & 3;
  const int ci  = (bid >> 2) & 127;
  const int bi  = bid >> 9;
  const int t   = threadIdx.x;
  const int r   = t >> 7;                      // pixel row 0..3
  const int px  = t & 127;                     // pixel col within quarter
  const int c   = px >> 2;                     // cell-local 0..31

  const size_t HW = (size_t)HDIM * WDIM;
  const int h   = 4 * ci + r;
  const int wpx = qs * 128 + px;
  const float* xp = x + (size_t)bi * NCH * HW + (size_t)h * WDIM + wpx;

  // ---- prefetch x: 16 coalesced 256B loads, in flight across the gather
  float xv[16];
  #pragma unroll
  for (int e = 0; e < 16; ++e) xv[e] = xp[(size_t)e * HW];

  // ---- gather: 33 f32 rowsum slots -> LDS
  {
    const int w8 = t >> 6;                     // wave 0..7
    const int l  = t & 63;
    const int u  = l >> 4, j = l & 15;
    const uint2* zb = zs + (size_t)bi * NPH * NPW * 64;
    const bool vh0 = (ci > 0), vh1 = (ci < NPH);
    const int ph0c = vh0 ? ci - 1 : 0;
    const int ph1c = vh1 ? ci : NPH - 1;
    for (int s = w8; s < 33; s += 8) {
      const int pw = qs * 32 - 1 + s;
      const bool vw = ((unsigned)pw <= (unsigned)(NPW - 1));
      const int pwc = vw ? pw : 0;
      uint2 z0 = zb[((size_t)ph0c * NPW + pwc) * 64 + l];
      uint2 z1 = zb[((size_t)ph1c * NPW + pwc) * 64 + l];
      if (!(vw && vh0)) { z0.x = 0u; z0.y = 0u; }
      if (!(vw && vh1)) { z1.x = 0u; z1.y = 0u; }
      float* rs = &RS[s * 260 + j];
      rs[16 * (4 * u + 0)] = blo2f(z0.x) + blo2f(z1.x);
      rs[16 * (4 * u + 1)] = bhi2f(z0.x) + bhi2f(z1.x);
      rs[16 * (4 * u + 2)] = blo2f(z0.y) + blo2f(z1.y);
      rs[16 * (4 * u + 3)] = bhi2f(z0.y) + bhi2f(z1.y);
    }
  }
  __syncthreads();

  // ---- matvec: out = x - (RS[c]+RS[c+1]) * x / cnt   (f32, no unpack)
  const int cj = qs * 32 + c;                  // global cell col
  const float cnth = 2.0f - (ci == 0) - (ci == NCELL - 1);
  const float cntw = 2.0f - (cj == 0) - (cj == NCELL - 1);
  const float sc = 1.0f / (cnth * cntw);

  const float* rsA = &RS[c * 260];
  const float* rsB = &RS[(c + 1) * 260];
  float* po = out + (size_t)bi * NCH * HW + (size_t)h * WDIM + wpx;
  #pragma unroll
  for (int co = 0; co < 16; ++co) {
    float acc = 0.f;
    #pragma unroll
    for (int k = 0; k < 4; ++k) {
      const float4 A = *(const float4*)(rsA + 16 * co + 4 * k);  // broadcast x4
      const float4 B = *(const float4*)(rsB + 16 * co + 4 * k);
      acc += (A.x + B.x) * xv[4 * k + 0];
      acc += (A.y + B.y) * xv[4 * k + 1];
      acc += (A.z + B.z) * xv[4 * k + 2];
      acc += (A.w + B.w) * xv[4 * k + 3];
    }
    po[(size_t)co * HW] = xv[co] - sc * acc;   // 256B contiguous per instr
  }
}

extern "C" void kernel_launch(void* const* d_in, const int* in_sizes, int n_in,
                              void* d_out, int out_size, void* d_ws, size_t ws_size,
                              hipStream_t stream) {
  const float* x = (const float*)d_in[0];
  float* out = (float*)d_out;
  uint2* zs = (uint2*)d_ws;                    // 32258*512B = 16.5 MB

  llr_zs<<<dim3(ZS_NBLK), dim3(256), 0, stream>>>(x, zs);
  llr_q<<<dim3(Q_NBLK), dim3(512), 0, stream>>>(x, zs, out);
}